// Round 1
// baseline (67.166 us; speedup 1.0000x reference)
//
#include <hip/hip_runtime.h>
#include <hip/hip_bf16.h>

#define F_DIM 64
#define B_DIM 64
#define C_DIM 1024
#define BM 64
#define BN 128
#define BK 64
#define NT (C_DIM / BK)   // 16 K-steps

using f32x4  = __attribute__((ext_vector_type(4))) float;
using bf16x8 = __attribute__((ext_vector_type(8))) short;
using s16x4  = __attribute__((ext_vector_type(4))) short;

// fp32 -> bf16 round-to-nearest-even (inputs are finite; no NaN path needed)
static __device__ __forceinline__ short f2bf(float f) {
    unsigned u = __float_as_uint(f);
    unsigned r = (u + 0x7fffu + ((u >> 16) & 1u)) >> 16;
    return (short)r;
}

__global__ __launch_bounds__(256, 2)
void channelfc_kernel(const float* __restrict__ x,
                      const float* __restrict__ w,
                      const float* __restrict__ bias,
                      float* __restrict__ out)
{
    const int f     = blockIdx.y;
    const int ocol0 = blockIdx.x * BN;
    const int tid   = threadIdx.x;
    const int lane  = tid & 63;
    const int wid   = tid >> 6;
    const int wr    = wid >> 1;   // wave M half (0..1) -> rows wr*32..+32
    const int wc    = wid & 1;    // wave N half (0..1) -> cols wc*64..+64

    // bf16 tiles, XOR-swizzled: element (row, byte) lives at row*128 + (byte ^ ((row&7)<<4))
    // (T2: without this, ds_read_b128 at row-stride 128B is a 32-way bank conflict)
    __shared__ short sA[2][BM * BK];   // 8 KB per buffer  (X tile: row = b, col = k)
    __shared__ short sB[2][BN * BK];   // 16 KB per buffer (W tile: row = o, col = k)

    const float* xA = x + (size_t)f * C_DIM;                       // + b*(F*C) + c
    const float* wB = w + ((size_t)f * C_DIM + ocol0) * C_DIM;     // + o*C + c

    f32x4 ra[4];   // A staging: 1024 float4 / 256 thr = 4 each
    f32x4 rb[8];   // B staging: 2048 float4 / 256 thr = 8 each

    auto load_tile = [&](int t) {
        const int k0 = t * BK;
        #pragma unroll
        for (int i = 0; i < 4; ++i) {
            int id = i * 256 + tid, row = id >> 4, k4 = id & 15;   // 16 float4 per row
            ra[i] = *(const f32x4*)(xA + (size_t)row * (F_DIM * C_DIM) + k0 + k4 * 4);
        }
        #pragma unroll
        for (int i = 0; i < 8; ++i) {
            int id = i * 256 + tid, row = id >> 4, k4 = id & 15;
            rb[i] = *(const f32x4*)(wB + (size_t)row * C_DIM + k0 + k4 * 4);
        }
    };

    auto store_tile = [&](int buf) {
        #pragma unroll
        for (int i = 0; i < 4; ++i) {
            int id = i * 256 + tid, row = id >> 4, k4 = id & 15;
            int byte = (k4 * 8) ^ ((row & 7) << 4);                // 8B store, swizzle is 16B-granular -> stays 8B-aligned
            s16x4 v; v[0]=f2bf(ra[i][0]); v[1]=f2bf(ra[i][1]); v[2]=f2bf(ra[i][2]); v[3]=f2bf(ra[i][3]);
            *(s16x4*)((char*)&sA[buf][0] + row * 128 + byte) = v;
        }
        #pragma unroll
        for (int i = 0; i < 8; ++i) {
            int id = i * 256 + tid, row = id >> 4, k4 = id & 15;
            int byte = (k4 * 8) ^ ((row & 7) << 4);
            s16x4 v; v[0]=f2bf(rb[i][0]); v[1]=f2bf(rb[i][1]); v[2]=f2bf(rb[i][2]); v[3]=f2bf(rb[i][3]);
            *(s16x4*)((char*)&sB[buf][0] + row * 128 + byte) = v;
        }
    };

    f32x4 acc[2][4] = {};   // wave sub-tile 32x64 = 2 M-frags x 4 N-frags

    load_tile(0);
    // Single barrier per iteration is sufficient:
    //  - compute(t) reads buf[t&1] AFTER barrier(t); store(t) wrote it before barrier(t).
    //  - store(t) on buf[t&1] happens after barrier(t-1); compute(t-2) on same buffer
    //    precedes barrier(t-1) in every wave's program order. No WAR race.
    for (int t = 0; t < NT; ++t) {
        const int buf = t & 1;
        store_tile(buf);                     // waits on vmcnt via register deps only
        if (t + 1 < NT) load_tile(t + 1);    // prefetch into regs; survives the barrier (T14)
        __syncthreads();
        #pragma unroll
        for (int ks = 0; ks < 2; ++ks) {
            const int kbyte = ks * 64 + (lane >> 4) * 16;   // frag: k = ks*32 + (lane>>4)*8 + j
            bf16x8 af[2], bfr[4];
            #pragma unroll
            for (int mt = 0; mt < 2; ++mt) {
                int row = wr * 32 + mt * 16 + (lane & 15);
                af[mt] = *(const bf16x8*)((const char*)&sA[buf][0] + row * 128 + (kbyte ^ ((row & 7) << 4)));
            }
            #pragma unroll
            for (int nt = 0; nt < 4; ++nt) {
                int row = wc * 64 + nt * 16 + (lane & 15);
                bfr[nt] = *(const bf16x8*)((const char*)&sB[buf][0] + row * 128 + (kbyte ^ ((row & 7) << 4)));
            }
            #pragma unroll
            for (int mt = 0; mt < 2; ++mt)
                #pragma unroll
                for (int nt = 0; nt < 4; ++nt)
                    acc[mt][nt] = __builtin_amdgcn_mfma_f32_16x16x32_bf16(af[mt], bfr[nt], acc[mt][nt], 0, 0, 0);
        }
    }

    // Epilogue. C/D layout (m89-verified): col = lane&15 (from B operand -> o), row = (lane>>4)*4 + reg (-> b)
    const int ncol_base = ocol0 + wc * 64 + (lane & 15);
    const int mrow_base = wr * 32 + (lane >> 4) * 4;
    #pragma unroll
    for (int nt = 0; nt < 4; ++nt) {
        const int o  = ncol_base + nt * 16;
        const float bv = bias[f * C_DIM + o];
        #pragma unroll
        for (int mt = 0; mt < 2; ++mt) {
            #pragma unroll
            for (int r = 0; r < 4; ++r) {
                const int b = mrow_base + mt * 16 + r;
                out[((size_t)b * F_DIM + f) * C_DIM + o] = acc[mt][nt][r] + bv;
            }
        }
    }
}

extern "C" void kernel_launch(void* const* d_in, const int* in_sizes, int n_in,
                              void* d_out, int out_size, void* d_ws, size_t ws_size,
                              hipStream_t stream) {
    const float* x    = (const float*)d_in[0];
    const float* w    = (const float*)d_in[1];
    const float* bias = (const float*)d_in[2];
    float* out        = (float*)d_out;
    dim3 grid(C_DIM / BN, F_DIM);   // (8 o-tiles, 64 features); blocks sharing f are adjacent -> X_f L2 reuse
    channelfc_kernel<<<grid, dim3(256), 0, stream>>>(x, w, bias, out);
}

// Round 2
// 58.698 us; speedup vs baseline: 1.1443x; 1.1443x over previous
//
#include <hip/hip_runtime.h>
#include <hip/hip_bf16.h>

#define F_DIM 64
#define B_DIM 64
#define C_DIM 1024
#define BM 64
#define BN 128
#define BK 64
#define NT (C_DIM / BK)   // 16 K-steps

using f32x4  = __attribute__((ext_vector_type(4))) float;
using bf16x8 = __attribute__((ext_vector_type(8))) short;
using s16x4  = __attribute__((ext_vector_type(4))) short;

// fp32 -> bf16 round-to-nearest-even (inputs are finite; no NaN path needed)
static __device__ __forceinline__ short f2bf(float f) {
    unsigned u = __float_as_uint(f);
    unsigned r = (u + 0x7fffu + ((u >> 16) & 1u)) >> 16;
    return (short)r;
}

__global__ __launch_bounds__(256, 2)
void channelfc_kernel(const float* __restrict__ x,
                      const float* __restrict__ w,
                      const float* __restrict__ bias,
                      float* __restrict__ out)
{
    // T1 XCD swizzle: dispatcher round-robins block n -> XCD n%8 (heuristic,
    // perf-only). Give XCD x features {x, x+8, ...} with all 8 o-tiles of one
    // f CONSECUTIVE on that XCD -> X_f (262 KB) is HBM-fetched once, then
    // L2-resident for the other 7 o-tile blocks. Without this, the 8 blocks
    // of f land on 8 different XCDs and X is re-fetched 8x (~+118 MB, the
    // entire gap between measured 67 us and the 48 us traffic floor).
    const int n    = blockIdx.x;       // 0..511
    const int xcd  = n & 7;
    const int j    = n >> 3;           // 0..63 within this XCD
    const int f    = xcd + 8 * (j >> 3);
    const int bx   = j & 7;            // o-tile index
    const int ocol0 = bx * BN;

    const int tid   = threadIdx.x;
    const int lane  = tid & 63;
    const int wid   = tid >> 6;
    const int wr    = wid >> 1;   // wave M half (0..1) -> rows wr*32..+32
    const int wc    = wid & 1;    // wave N half (0..1) -> cols wc*64..+64

    // bf16 tiles, XOR-swizzled: element (row, byte) lives at row*128 + (byte ^ ((row&7)<<4))
    // (T2: without this, ds_read_b128 at row-stride 128B is a 32-way bank conflict)
    __shared__ short sA[2][BM * BK];   // 8 KB per buffer  (X tile: row = b, col = k)
    __shared__ short sB[2][BN * BK];   // 16 KB per buffer (W tile: row = o, col = k)

    const float* xA = x + (size_t)f * C_DIM;                       // + b*(F*C) + c
    const float* wB = w + ((size_t)f * C_DIM + ocol0) * C_DIM;     // + o*C + c

    f32x4 ra[4];   // A staging: 1024 float4 / 256 thr = 4 each
    f32x4 rb[8];   // B staging: 2048 float4 / 256 thr = 8 each

    auto load_tile = [&](int t) {
        const int k0 = t * BK;
        #pragma unroll
        for (int i = 0; i < 4; ++i) {
            int id = i * 256 + tid, row = id >> 4, k4 = id & 15;   // 16 float4 per row
            ra[i] = *(const f32x4*)(xA + (size_t)row * (F_DIM * C_DIM) + k0 + k4 * 4);
        }
        #pragma unroll
        for (int i = 0; i < 8; ++i) {
            int id = i * 256 + tid, row = id >> 4, k4 = id & 15;
            rb[i] = *(const f32x4*)(wB + (size_t)row * C_DIM + k0 + k4 * 4);
        }
    };

    auto store_tile = [&](int buf) {
        #pragma unroll
        for (int i = 0; i < 4; ++i) {
            int id = i * 256 + tid, row = id >> 4, k4 = id & 15;
            int byte = (k4 * 8) ^ ((row & 7) << 4);                // 8B store, swizzle is 16B-granular -> stays 8B-aligned
            s16x4 v; v[0]=f2bf(ra[i][0]); v[1]=f2bf(ra[i][1]); v[2]=f2bf(ra[i][2]); v[3]=f2bf(ra[i][3]);
            *(s16x4*)((char*)&sA[buf][0] + row * 128 + byte) = v;
        }
        #pragma unroll
        for (int i = 0; i < 8; ++i) {
            int id = i * 256 + tid, row = id >> 4, k4 = id & 15;
            int byte = (k4 * 8) ^ ((row & 7) << 4);
            s16x4 v; v[0]=f2bf(rb[i][0]); v[1]=f2bf(rb[i][1]); v[2]=f2bf(rb[i][2]); v[3]=f2bf(rb[i][3]);
            *(s16x4*)((char*)&sB[buf][0] + row * 128 + byte) = v;
        }
    };

    f32x4 acc[2][4] = {};   // wave sub-tile 32x64 = 2 M-frags x 4 N-frags

    load_tile(0);
    // Single barrier per iteration is sufficient:
    //  - compute(t) reads buf[t&1] AFTER barrier(t); store(t) wrote it before barrier(t).
    //  - store(t) on buf[t&1] happens after barrier(t-1); compute(t-2) on same buffer
    //    precedes barrier(t-1) in every wave's program order. No WAR race.
    for (int t = 0; t < NT; ++t) {
        const int buf = t & 1;
        store_tile(buf);                     // waits on vmcnt via register deps only
        if (t + 1 < NT) load_tile(t + 1);    // prefetch into regs; survives the barrier (T14)
        __syncthreads();
        #pragma unroll
        for (int ks = 0; ks < 2; ++ks) {
            const int kbyte = ks * 64 + (lane >> 4) * 16;   // frag: k = ks*32 + (lane>>4)*8 + j
            bf16x8 af[2], bfr[4];
            #pragma unroll
            for (int mt = 0; mt < 2; ++mt) {
                int row = wr * 32 + mt * 16 + (lane & 15);
                af[mt] = *(const bf16x8*)((const char*)&sA[buf][0] + row * 128 + (kbyte ^ ((row & 7) << 4)));
            }
            #pragma unroll
            for (int nt = 0; nt < 4; ++nt) {
                int row = wc * 64 + nt * 16 + (lane & 15);
                bfr[nt] = *(const bf16x8*)((const char*)&sB[buf][0] + row * 128 + (kbyte ^ ((row & 7) << 4)));
            }
            #pragma unroll
            for (int mt = 0; mt < 2; ++mt)
                #pragma unroll
                for (int nt = 0; nt < 4; ++nt)
                    acc[mt][nt] = __builtin_amdgcn_mfma_f32_16x16x32_bf16(af[mt], bfr[nt], acc[mt][nt], 0, 0, 0);
        }
    }

    // Epilogue. C/D layout (m89-verified): col = lane&15 (from B operand -> o), row = (lane>>4)*4 + reg (-> b)
    const int ncol_base = ocol0 + wc * 64 + (lane & 15);
    const int mrow_base = wr * 32 + (lane >> 4) * 4;
    #pragma unroll
    for (int nt = 0; nt < 4; ++nt) {
        const int o  = ncol_base + nt * 16;
        const float bv = bias[f * C_DIM + o];
        #pragma unroll
        for (int mt = 0; mt < 2; ++mt) {
            #pragma unroll
            for (int r = 0; r < 4; ++r) {
                const int b = mrow_base + mt * 16 + r;
                out[((size_t)b * F_DIM + f) * C_DIM + o] = acc[mt][nt][r] + bv;
            }
        }
    }
}

extern "C" void kernel_launch(void* const* d_in, const int* in_sizes, int n_in,
                              void* d_out, int out_size, void* d_ws, size_t ws_size,
                              hipStream_t stream) {
    const float* x    = (const float*)d_in[0];
    const float* w    = (const float*)d_in[1];
    const float* bias = (const float*)d_in[2];
    float* out        = (float*)d_out;
    // 1-D grid (512 blocks) with explicit XCD-aware index decode in-kernel.
    channelfc_kernel<<<dim3(C_DIM / BN * F_DIM), dim3(256), 0, stream>>>(x, w, bias, out);
}